// Round 8
// baseline (278.192 us; speedup 1.0000x reference)
//
#include <hip/hip_runtime.h>
#include <hip/hip_bf16.h>
#include <math.h>

// ConvNeXt MLP + parallel MoE-LoRA, fp32 in/out, bf16-tolerance harness.
// B,H,W,C = 64,14,14,768 ; N_tok = 12544 = 98*128 ; HID = 3072 ; E=8,K=2,R=16.
//
//   h  = gelu(x @ w1 + b1)                GEMM1  [12544,768]x[768,3072]
//   sd = wt * gelu(x @ wdown)             GEMMd  [12544,768]x[768,128]  (fused as GEMM1 tail)
//   out = [h | sd] @ [w2 ; wup] + b2      GEMM2  [12544,3200]x[3200,768]
//
// R20 = R19 (252.5us; GEMMd fused as tail blocks) + epilogue rework:
//   MfmaUtil 33 / VALUBusy 38 -> epilogue VALU (~1200 cyc/wave: 48 outputs x
//   gelu+f2bf+48 scalar 2B stores) is comparable to the whole k-loop's MFMA.
//   1. SWAPPED MFMA operands: mfma(bfr, af) yields the transposed sub-tile;
//      lane holds m = base+row16, n = base+quad*4+i (4 CONSECUTIVE cols) ->
//      12 packed stores (ushort4/float4) instead of 48 scalar, float4 bias,
//      LoRA tki/tkp gather 16 -> 4 m-values/lane. Same math & rounding.
//   2. Fragment hoist: all 14 ds_reads at P0 (P1's lgkm drain becomes free).
//   Sync structure (barriers / issue points / counted vmcnt) is R17-exact;
//   hazard windows re-verified identical.

#define NTOK   12544
#define CDIM   768
#define HIDDIM 3072
#define KBIG   3200

typedef __attribute__((ext_vector_type(8))) short bf16x8;
typedef __attribute__((ext_vector_type(4))) float f32x4;

#define GLOBAL_AS(p) ((const __attribute__((address_space(1))) void*)(p))
#define LDS_AS(p)    ((__attribute__((address_space(3))) void*)(p))
#define GLD(src, dst) __builtin_amdgcn_global_load_lds(GLOBAL_AS(src), LDS_AS(dst), 16, 0, 0)

__device__ inline unsigned short f2bf(float f) {
    unsigned int x = __float_as_uint(f);
    x += 0x7fffu + ((x >> 16) & 1u);   // RNE
    return (unsigned short)(x >> 16);
}

// tanh-form GELU, branch-free; max |err| ~4.3e-4 vs exact erf form.
__device__ inline float gelu_fast(float x) {
    float x3 = x * x * x;
    float u2 = 1.5957691216057308f * x + 0.07135481627260025f * x3;
    float e = __expf(-u2);
    return x * __builtin_amdgcn_rcpf(1.0f + e);
}

// ---------------- fused prep: cast_x + 3 transposes (64x64) + pack_wdown -------
__global__ void __launch_bounds__(256) prep_kernel(
        const float* __restrict__ x, const float* __restrict__ w1,
        const float* __restrict__ w2, const float* __restrict__ wup,
        const float* __restrict__ wdn,
        unsigned short* __restrict__ xb, unsigned short* __restrict__ w1t,
        unsigned short* __restrict__ B2t, unsigned short* __restrict__ wdt) {
    __shared__ float tile[64][65];
    const int b = blockIdx.x, tid = threadIdx.x;
    if (b < 9408) {                      // cast x -> bf16, float4->ushort4
        int i = b * 256 + tid;
        float4 v = ((const float4*)x)[i];
        ushort4 o;
        o.x = f2bf(v.x); o.y = f2bf(v.y); o.z = f2bf(v.z); o.w = f2bf(v.w);
        ((ushort4*)xb)[i] = o;
        return;
    }
    if (b < 10584) {                     // 64x64 transpose tiles
        const float* in; unsigned short* outp; int Ccols, out_ld, out_off, bx, by;
        if (b < 9984)       { int t = b - 9408;  in = w1;  outp = w1t; Ccols = 3072; out_ld = 768;  out_off = 0;    bx = t % 48; by = t / 48; }
        else if (b < 10560) { int t = b - 9984;  in = w2;  outp = B2t; Ccols = 768;  out_ld = 3200; out_off = 0;    bx = t % 12; by = t / 12; }
        else                { int t = b - 10560; in = wup; outp = B2t; Ccols = 768;  out_ld = 3200; out_off = 3072; bx = t % 12; by = t / 12; }
        const int c0 = bx * 64, r0 = by * 64;
        #pragma unroll
        for (int p = 0; p < 4; ++p) {
            int idx = p * 256 + tid;
            int r = idx >> 4, c4 = (idx & 15) * 4;
            float4 v = *(const float4*)&in[(size_t)(r0 + r) * Ccols + c0 + c4];
            tile[r][c4 + 0] = v.x; tile[r][c4 + 1] = v.y;
            tile[r][c4 + 2] = v.z; tile[r][c4 + 3] = v.w;
        }
        __syncthreads();
        #pragma unroll
        for (int p = 0; p < 2; ++p) {
            int u = p * 256 + tid;
            int cc = u >> 3, r8 = (u & 7) * 8;
            uint4 pk;
            pk.x = (unsigned)f2bf(tile[r8 + 0][cc]) | ((unsigned)f2bf(tile[r8 + 1][cc]) << 16);
            pk.y = (unsigned)f2bf(tile[r8 + 2][cc]) | ((unsigned)f2bf(tile[r8 + 3][cc]) << 16);
            pk.z = (unsigned)f2bf(tile[r8 + 4][cc]) | ((unsigned)f2bf(tile[r8 + 5][cc]) << 16);
            pk.w = (unsigned)f2bf(tile[r8 + 6][cc]) | ((unsigned)f2bf(tile[r8 + 7][cc]) << 16);
            *(uint4*)&outp[(size_t)(c0 + cc) * out_ld + out_off + r0 + r8] = pk;
        }
        return;
    }
    {   // pack_wdown: wdt[j][c] = wdown[e][c][r], j = e*16+r
        int idx = (b - 10584) * 256 + tid;
        int j = idx / 768, c = idx - j * 768;
        int e = j >> 4, r = j & 15;
        wdt[idx] = f2bf(wdn[((size_t)e * 768 + c) * 16 + r]);
    }
}

// ---- 4-phase BK=64 GEMM phase (R17-proven protocol), frags pre-loaded -------
// Per phase: issue prefetch -> barrier -> lgkmcnt(0) -> setprio(1) MFMA
// cluster (SWAPPED operands: mfma(bfr, af) -> transposed sub-tile) setprio(0)
// -> [tail vmcnt(VMN)] -> barrier. Tail vmcnt(VMN) leaves only the newest
// B-tile (VMN GLDs) outstanding; never drains to 0 in the loop.
template <int NFRAG, int P, bool TAILV, int VMN, class Issue>
__device__ __forceinline__ void phase4s(
        f32x4 (&acc)[4][NFRAG], const bf16x8 (&af)[4][2],
        const bf16x8 (&bfr)[NFRAG][2], Issue issue) {
    issue();
    __builtin_amdgcn_s_barrier();
    asm volatile("s_waitcnt lgkmcnt(0)" ::: "memory");
    __builtin_amdgcn_sched_barrier(0);
    __builtin_amdgcn_s_setprio(1);
    #pragma unroll
    for (int f = 0; f < 2; ++f)
        #pragma unroll
        for (int nf = 0; nf < NFRAG; ++nf)
            #pragma unroll
            for (int k = 0; k < 2; ++k)
                acc[2 * P + f][nf] = __builtin_amdgcn_mfma_f32_16x16x32_bf16(
                    bfr[nf][k], af[2 * P + f][k], acc[2 * P + f][nf], 0, 0, 0);
    __builtin_amdgcn_s_setprio(0);
    if (TAILV) {
        if constexpr (VMN == 3) asm volatile("s_waitcnt vmcnt(3)" ::: "memory");
        else                    asm volatile("s_waitcnt vmcnt(2)" ::: "memory");
    }
    __builtin_amdgcn_s_barrier();
    __builtin_amdgcn_sched_barrier(0);
}

// ---- 128x192 BK=64, 80KB LDS, 2 blocks/CU, 8 waves (2M x 4N) ----------------
// Main path: R17 schedule. LORA tail blocks (orig >= MAIN): separate 128x128
// loop (A=xb shared, B=wdt), EPI1 epilogue.
// Swapped C^T lane layout: acc[mi][nf][i] = C[m0+wm+mi*16+row16]
//                                            [n0+wn+nf*16+quad*4+i].
// EPI 0: gelu(acc + bias) -> bf16 apOut (ushort4)        (GEMM1)
// EPI 2: acc + bias       -> f32 fOut (float4)           (GEMM2)
template <int EPI, int NBX, bool LORA>
__global__ void __launch_bounds__(512, 4)
gemm4_kernel(const unsigned short* __restrict__ A, int lda,
             const unsigned short* __restrict__ Bt, int ldb,
             int kTiles, const float* __restrict__ bias,
             unsigned short* __restrict__ apOut, float* __restrict__ fOut,
             const int* __restrict__ tki, const float* __restrict__ tkp,
             const unsigned short* __restrict__ Bt2) {
    __shared__ __align__(1024) char ldsraw[81920];     // 80 KiB -> 2 blocks/CU
    char* ldsA = ldsraw;                                // [2] x 16 KB
    char* ldsB = ldsraw + 32768;                        // [2] x 24 KB (16 KB lora)

    constexpr int MAIN = NBX * (NTOK / 128);            // main-grid blocks (%8==0)
    const int orig = blockIdx.x;

    const int tid  = threadIdx.x;
    const int wave = tid >> 6;
    const int lane = tid & 63;
    const int row16 = lane & 15;
    const int quad  = lane >> 4;
    const int wm = (wave >> 2) << 6;      // 0 / 64
    const int swz = (row16 & 7) << 4;
    const int aFB = ((wm + row16) << 7) + (quad << 4);
    const int aX0 = (aFB ^ swz), aX1 = ((aFB + 64) ^ swz);

    // staging decomposition (shared): dest linear in tid; source pre-swizzled
    // with the same 3-bit involution so LDS content is swizzle-stored.
    const int d  = tid << 4;
    const int s  = d ^ (((d >> 7) & 7) << 4);
    const int sr = s >> 7;                // source row 0..63 (per 8KB unit)
    const int sc = (s & 127) >> 1;        // source col elem (16B chunk)
    const int ldsW = wave << 10;

    if constexpr (LORA) {
        if (orig >= MAIN) {
            // ---------------- LoRA tail path: 128 x 128, K = kTiles*64 ------
            const int m0 = (orig - MAIN) * 128;
            const int wn = (wave & 3) << 5;            // 0/32/64/96
            const int bFB = ((wn + row16) << 7) + (quad << 4);
            const int bX0 = (bFB ^ swz) + 32768, bX1 = ((bFB + 64) ^ swz) + 32768;
            const char* aSrc = (const char*)(A + (size_t)(m0 + sr) * lda + sc);
            const char* bSrc = (const char*)(Bt2 + (size_t)sr * CDIM + sc);
            const size_t aStep = (size_t)64 * lda * 2;
            const size_t bStep = (size_t)64 * CDIM * 2;
            auto issueA = [&](int b, int tk) {         // 128 rows = 2 GLD
                const char* sp = aSrc + (size_t)tk * 128;
                char* dp = ldsA + b * 16384 + ldsW;
                GLD(sp, dp);
                GLD(sp + aStep, dp + 8192);
            };
            auto issueB = [&](int b, int tk) {         // 128 rows = 2 GLD
                const char* sp = bSrc + (size_t)tk * 128;
                char* dp = ldsB + b * 16384 + ldsW;
                GLD(sp, dp);
                GLD(sp + bStep, dp + 8192);
            };
            f32x4 acc[4][2] = {};
            issueB(0, 0); issueA(0, 0); issueB(1, 1);
            asm volatile("s_waitcnt vmcnt(2)" ::: "memory");
            __builtin_amdgcn_s_barrier();
            __builtin_amdgcn_sched_barrier(0);
            const int nIter = kTiles >> 1;
            for (int it = 0; it < nIter; ++it) {
                const int t  = it * 2;
                const int t2 = (t + 2 < kTiles) ? t + 2 : 0;
                const int t3 = (t + 3 < kTiles) ? t + 3 : 0;
                bf16x8 af[4][2], bfr[2][2];
                #pragma unroll
                for (int mi = 0; mi < 4; ++mi) {
                    af[mi][0] = *(const bf16x8*)(ldsraw + aX0 + mi * 2048);
                    af[mi][1] = *(const bf16x8*)(ldsraw + aX1 + mi * 2048);
                }
                #pragma unroll
                for (int nf = 0; nf < 2; ++nf) {
                    bfr[nf][0] = *(const bf16x8*)(ldsraw + bX0 + nf * 2048);
                    bfr[nf][1] = *(const bf16x8*)(ldsraw + bX1 + nf * 2048);
                }
                phase4s<2, 0, false, 2>(acc, af, bfr, [&]{ issueA(1, t + 1); });
                phase4s<2, 1, true , 2>(acc, af, bfr, [&]{ issueB(0, t2); });
                #pragma unroll
                for (int mi = 0; mi < 4; ++mi) {
                    af[mi][0] = *(const bf16x8*)(ldsraw + aX0 + 16384 + mi * 2048);
                    af[mi][1] = *(const bf16x8*)(ldsraw + aX1 + 16384 + mi * 2048);
                }
                #pragma unroll
                for (int nf = 0; nf < 2; ++nf) {
                    bfr[nf][0] = *(const bf16x8*)(ldsraw + bX0 + 16384 + nf * 2048);
                    bfr[nf][1] = *(const bf16x8*)(ldsraw + bX1 + 16384 + nf * 2048);
                }
                phase4s<2, 0, false, 2>(acc, af, bfr, [&]{ issueA(0, t2); });
                phase4s<2, 1, true , 2>(acc, af, bfr, [&]{ issueB(1, t3); });
            }
            asm volatile("s_waitcnt vmcnt(0)" ::: "memory");
            // swapped epilogue: m = m0+wm+mi*16+row16 ; n = wn+nf*16+quad*4+i
            #pragma unroll
            for (int mi = 0; mi < 4; ++mi) {
                const int m = m0 + wm + mi * 16 + row16;
                const int i0 = tki[m * 2], i1 = tki[m * 2 + 1];
                const float p0 = tkp[m * 2], p1 = tkp[m * 2 + 1];
                #pragma unroll
                for (int nf = 0; nf < 2; ++nf) {
                    const int nb = wn + nf * 16 + quad * 4;
                    const int e = nb >> 4;           // uniform over i (quad*4 < 16)
                    const float wt = (i0 == e ? p0 : 0.f) + (i1 == e ? p1 : 0.f);
                    ushort4 o;
                    o.x = f2bf(gelu_fast(acc[mi][nf][0]) * wt);
                    o.y = f2bf(gelu_fast(acc[mi][nf][1]) * wt);
                    o.z = f2bf(gelu_fast(acc[mi][nf][2]) * wt);
                    o.w = f2bf(gelu_fast(acc[mi][nf][3]) * wt);
                    *(ushort4*)&apOut[(size_t)m * KBIG + 3072 + nb] = o;
                }
            }
            return;
        }
    }

    // ---------------- main path (R17 schedule) -------------------------------
    // bijective XCD swizzle (MAIN%8==0), bx-fast: each XCD's contiguous wgid
    // chunk shares A row-panels (L2 dedup).
    constexpr int qq = MAIN / 8;
    const int xcd = orig & 7, within = orig >> 3;
    const int wgid = xcd * qq + within;
    const int bx = wgid % NBX, by = wgid / NBX;

    const int m0 = by * 128;
    const int n0 = bx * 192;
    const int wn = (wave & 3) * 48;       // 0 / 48 / 96 / 144
    const int bFB = ((wn + row16) << 7) + (quad << 4);
    const int bX0 = (bFB ^ swz) + 32768, bX1 = ((bFB + 64) ^ swz) + 32768;

    const char* aSrc = (const char*)(A + (size_t)(m0 + sr) * lda + sc);
    const char* bSrc = (const char*)(Bt + (size_t)(n0 + sr) * ldb + sc);
    const size_t aStep = (size_t)64 * lda * 2;   // 64 rows, bytes
    const size_t bStep = (size_t)64 * ldb * 2;

    auto issueA = [&](int b, int tk) {           // 128 rows = 2 GLD
        const char* sp = aSrc + (size_t)tk * 128;
        char* dp = ldsA + b * 16384 + ldsW;
        GLD(sp, dp);
        GLD(sp + aStep, dp + 8192);
    };
    auto issueB = [&](int b, int tk) {           // 192 rows = 3 GLD
        const char* sp = bSrc + (size_t)tk * 128;
        char* dp = ldsB + b * 24576 + ldsW;
        GLD(sp, dp);
        GLD(sp + bStep, dp + 8192);
        GLD(sp + 2 * bStep, dp + 16384);
    };

    f32x4 acc[4][3] = {};

    // prologue: B(0)->b0, A(0)->a0, B(1)->b1; leave B(1)'s 3 outstanding
    issueB(0, 0);
    issueA(0, 0);
    issueB(1, 1);
    asm volatile("s_waitcnt vmcnt(3)" ::: "memory");
    __builtin_amdgcn_s_barrier();
    __builtin_amdgcn_sched_barrier(0);

    const int nIter = kTiles >> 1;
    for (int it = 0; it < nIter; ++it) {
        const int t  = it * 2;
        const int t2 = (t + 2 < kTiles) ? t + 2 : 0;   // clamped (harmless re-stage)
        const int t3 = (t + 3 < kTiles) ? t + 3 : 0;
        bf16x8 af[4][2], bfr[3][2];
        #pragma unroll
        for (int mi = 0; mi < 4; ++mi) {
            af[mi][0] = *(const bf16x8*)(ldsraw + aX0 + mi * 2048);
            af[mi][1] = *(const bf16x8*)(ldsraw + aX1 + mi * 2048);
        }
        #pragma unroll
        for (int nf = 0; nf < 3; ++nf) {
            bfr[nf][0] = *(const bf16x8*)(ldsraw + bX0 + nf * 2048);
            bfr[nf][1] = *(const bf16x8*)(ldsraw + bX1 + nf * 2048);
        }
        phase4s<3, 0, false, 3>(acc, af, bfr, [&]{ issueA(1, t + 1); });
        phase4s<3, 1, true , 3>(acc, af, bfr, [&]{ issueB(0, t2); });
        #pragma unroll
        for (int mi = 0; mi < 4; ++mi) {
            af[mi][0] = *(const bf16x8*)(ldsraw + aX0 + 16384 + mi * 2048);
            af[mi][1] = *(const bf16x8*)(ldsraw + aX1 + 16384 + mi * 2048);
        }
        #pragma unroll
        for (int nf = 0; nf < 3; ++nf) {
            bfr[nf][0] = *(const bf16x8*)(ldsraw + bX0 + 24576 + nf * 2048);
            bfr[nf][1] = *(const bf16x8*)(ldsraw + bX1 + 24576 + nf * 2048);
        }
        phase4s<3, 0, false, 3>(acc, af, bfr, [&]{ issueA(0, t2); });
        phase4s<3, 1, true , 3>(acc, af, bfr, [&]{ issueB(1, t3); });
    }
    asm volatile("s_waitcnt vmcnt(0)" ::: "memory");

    // swapped epilogue: m = m0+wm+mi*16+row16 ; n = n0+wn+nf*16+quad*4+i
    float4 bv[3];
    #pragma unroll
    for (int nf = 0; nf < 3; ++nf)
        bv[nf] = *(const float4*)&bias[n0 + wn + nf * 16 + quad * 4];
    #pragma unroll
    for (int mi = 0; mi < 4; ++mi) {
        const int m = m0 + wm + mi * 16 + row16;
        #pragma unroll
        for (int nf = 0; nf < 3; ++nf) {
            const int nb = n0 + wn + nf * 16 + quad * 4;
            if (EPI == 0) {
                ushort4 o;
                o.x = f2bf(gelu_fast(acc[mi][nf][0] + bv[nf].x));
                o.y = f2bf(gelu_fast(acc[mi][nf][1] + bv[nf].y));
                o.z = f2bf(gelu_fast(acc[mi][nf][2] + bv[nf].z));
                o.w = f2bf(gelu_fast(acc[mi][nf][3] + bv[nf].w));
                *(ushort4*)&apOut[(size_t)m * KBIG + nb] = o;
            } else {
                float4 v;
                v.x = acc[mi][nf][0] + bv[nf].x;
                v.y = acc[mi][nf][1] + bv[nf].y;
                v.z = acc[mi][nf][2] + bv[nf].z;
                v.w = acc[mi][nf][3] + bv[nf].w;
                *(float4*)&fOut[(size_t)m * CDIM + nb] = v;
            }
        }
    }
}

// ---------------- launch ----------------

extern "C" void kernel_launch(void* const* d_in, const int* in_sizes, int n_in,
                              void* d_out, int out_size, void* d_ws, size_t ws_size,
                              hipStream_t stream) {
    const float* x   = (const float*)d_in[0];
    const float* tkp = (const float*)d_in[1];
    const int*   tki = (const int*)d_in[2];
    const float* w1  = (const float*)d_in[3];
    const float* b1  = (const float*)d_in[4];
    const float* w2  = (const float*)d_in[5];
    const float* b2  = (const float*)d_in[6];
    const float* wdn = (const float*)d_in[7];
    const float* wup = (const float*)d_in[8];
    float* out = (float*)d_out;

    unsigned short* xb  = (unsigned short*)d_ws;
    unsigned short* w1t = xb  + (size_t)NTOK * CDIM;      // 3072 x 768
    unsigned short* B2t = w1t + (size_t)HIDDIM * CDIM;    // 768 x 3200
    unsigned short* wdt = B2t + (size_t)CDIM * KBIG;      // 128 x 768
    unsigned short* Ap  = wdt + (size_t)128 * CDIM;       // 12544 x 3200

    prep_kernel<<<dim3(10968), 256, 0, stream>>>(x, w1, w2, wup, wdn,
                                                 xb, w1t, B2t, wdt);

    // GEMM1 + GEMMd fused grid: 1568 main blocks (128x192) + 98 LoRA tail
    // blocks (128x128, dispatched last -> fill the scheduling tail).
    gemm4_kernel<0, HIDDIM / 192, true>
        <<<dim3((HIDDIM / 192 + 1) * (NTOK / 128)), 512, 0, stream>>>(
        xb, CDIM, w1t, CDIM, CDIM / 64, b1, Ap, nullptr, tki, tkp, wdt);
    // GEMM2: out = Ap @ B2t^T + b2 ; 128x192, 2 blocks/CU, 392 blocks swizzled
    gemm4_kernel<2, CDIM / 192, false>
        <<<dim3((CDIM / 192) * (NTOK / 128)), 512, 0, stream>>>(
        Ap, KBIG, B2t, KBIG, KBIG / 64, b2, nullptr, out, nullptr, nullptr, nullptr);
}

// Round 10
// 247.574 us; speedup vs baseline: 1.1237x; 1.1237x over previous
//
#include <hip/hip_runtime.h>
#include <hip/hip_bf16.h>
#include <math.h>

// ConvNeXt MLP + parallel MoE-LoRA, fp32 in/out, bf16-tolerance harness.
// B,H,W,C = 64,14,14,768 ; N_tok = 12544 = 98*128 ; HID = 3072 ; E=8,K=2,R=16.
//
//   h  = gelu(x @ w1 + b1)                GEMM1  [12544,768]x[768,3072]
//   sd = wt * gelu(x @ wdown)             GEMMd  [12544,768]x[768,128]  (fused as GEMM1 tail)
//   out = [h | sd] @ [w2 ; wup] + b2      GEMM2  [12544,3200]x[3200,768]
//
// R22: R21 post-mortem: FAILED (absmax 0.286). The cross-tile frag reads at
// end of ph1/ph3 sat between the wave's OWN vmcnt(3) and the barrier --
// vmcnt is per-wave, but fragments span rows staged by OTHER waves whose
// GLDs had not landed. RULE: a ds_read of staged data may only sit after a
// {vmcnt-tail -> s_barrier} pair, never between them.
// R22 keeps only the SAFE half of the pipelining:
//   - cross-tile reads (P0 set: af0 + bfr of next buffer): R19 placement,
//     after the closing barrier, before the next GLD issue.
//   - intra-tile reads (P1's af1 = slices 2-3 of the same landed+barriered
//     A buffer): early, at end of ph0/ph2. Data landed before the tile's
//     first phase; the overwriting GLD (ph2 issueA) is only issued after the
//     ph1-close barrier, and this wave's read completes at its ph1
//     lgkmcnt(0) before reaching that barrier. ph1/ph3's lgkm drain is free.
// Everything else R19-exact: 128x192 BK=64, 80KB LDS, 2 blocks/CU, counted
// vmcnt tails (never 0), 3-bit both-sides swizzle, XCD-bijective grid,
// GEMMd as 98 LoRA tail blocks, scalar-store epilogue (WRITE exactly 80MB).

#define NTOK   12544
#define CDIM   768
#define HIDDIM 3072
#define KBIG   3200

typedef __attribute__((ext_vector_type(8))) short bf16x8;
typedef __attribute__((ext_vector_type(4))) float f32x4;

#define GLOBAL_AS(p) ((const __attribute__((address_space(1))) void*)(p))
#define LDS_AS(p)    ((__attribute__((address_space(3))) void*)(p))
#define GLD(src, dst) __builtin_amdgcn_global_load_lds(GLOBAL_AS(src), LDS_AS(dst), 16, 0, 0)

__device__ inline unsigned short f2bf(float f) {
    unsigned int x = __float_as_uint(f);
    x += 0x7fffu + ((x >> 16) & 1u);   // RNE
    return (unsigned short)(x >> 16);
}

// tanh-form GELU, branch-free; max |err| ~4.3e-4 vs exact erf form.
__device__ inline float gelu_fast(float x) {
    float x3 = x * x * x;
    float u2 = 1.5957691216057308f * x + 0.07135481627260025f * x3;
    float e = __expf(-u2);
    return x * __builtin_amdgcn_rcpf(1.0f + e);
}

// ---------------- fused prep: cast_x + 3 transposes (64x64) + pack_wdown -------
__global__ void __launch_bounds__(256) prep_kernel(
        const float* __restrict__ x, const float* __restrict__ w1,
        const float* __restrict__ w2, const float* __restrict__ wup,
        const float* __restrict__ wdn,
        unsigned short* __restrict__ xb, unsigned short* __restrict__ w1t,
        unsigned short* __restrict__ B2t, unsigned short* __restrict__ wdt) {
    __shared__ float tile[64][65];
    const int b = blockIdx.x, tid = threadIdx.x;
    if (b < 9408) {                      // cast x -> bf16, float4->ushort4
        int i = b * 256 + tid;
        float4 v = ((const float4*)x)[i];
        ushort4 o;
        o.x = f2bf(v.x); o.y = f2bf(v.y); o.z = f2bf(v.z); o.w = f2bf(v.w);
        ((ushort4*)xb)[i] = o;
        return;
    }
    if (b < 10584) {                     // 64x64 transpose tiles
        const float* in; unsigned short* outp; int Ccols, out_ld, out_off, bx, by;
        if (b < 9984)       { int t = b - 9408;  in = w1;  outp = w1t; Ccols = 3072; out_ld = 768;  out_off = 0;    bx = t % 48; by = t / 48; }
        else if (b < 10560) { int t = b - 9984;  in = w2;  outp = B2t; Ccols = 768;  out_ld = 3200; out_off = 0;    bx = t % 12; by = t / 12; }
        else                { int t = b - 10560; in = wup; outp = B2t; Ccols = 768;  out_ld = 3200; out_off = 3072; bx = t % 12; by = t / 12; }
        const int c0 = bx * 64, r0 = by * 64;
        #pragma unroll
        for (int p = 0; p < 4; ++p) {
            int idx = p * 256 + tid;
            int r = idx >> 4, c4 = (idx & 15) * 4;
            float4 v = *(const float4*)&in[(size_t)(r0 + r) * Ccols + c0 + c4];
            tile[r][c4 + 0] = v.x; tile[r][c4 + 1] = v.y;
            tile[r][c4 + 2] = v.z; tile[r][c4 + 3] = v.w;
        }
        __syncthreads();
        #pragma unroll
        for (int p = 0; p < 2; ++p) {
            int u = p * 256 + tid;
            int cc = u >> 3, r8 = (u & 7) * 8;
            uint4 pk;
            pk.x = (unsigned)f2bf(tile[r8 + 0][cc]) | ((unsigned)f2bf(tile[r8 + 1][cc]) << 16);
            pk.y = (unsigned)f2bf(tile[r8 + 2][cc]) | ((unsigned)f2bf(tile[r8 + 3][cc]) << 16);
            pk.z = (unsigned)f2bf(tile[r8 + 4][cc]) | ((unsigned)f2bf(tile[r8 + 5][cc]) << 16);
            pk.w = (unsigned)f2bf(tile[r8 + 6][cc]) | ((unsigned)f2bf(tile[r8 + 7][cc]) << 16);
            *(uint4*)&outp[(size_t)(c0 + cc) * out_ld + out_off + r0 + r8] = pk;
        }
        return;
    }
    {   // pack_wdown: wdt[j][c] = wdown[e][c][r], j = e*16+r
        int idx = (b - 10584) * 256 + tid;
        int j = idx / 768, c = idx - j * 768;
        int e = j >> 4, r = j & 15;
        wdt[idx] = f2bf(wdn[((size_t)e * 768 + c) * 16 + r]);
    }
}

// ---- MFMA phase core (R17/R19-proven protocol, reads hoisted OUT) ----------
// issue -> barrier -> lgkmcnt(0) [waits frag reads issued before the call]
// -> sched_barrier -> setprio(1) MFMA cluster setprio(0).
template <int NFRAG, int A0, class Issue>
__device__ __forceinline__ void phaseC(
        f32x4 (&acc)[4][NFRAG], const bf16x8 (&af)[2][2],
        const bf16x8 (&bfr)[NFRAG][2], Issue issue) {
    issue();
    __builtin_amdgcn_s_barrier();
    asm volatile("s_waitcnt lgkmcnt(0)" ::: "memory");
    __builtin_amdgcn_sched_barrier(0);
    __builtin_amdgcn_s_setprio(1);
    #pragma unroll
    for (int f = 0; f < 2; ++f)
        #pragma unroll
        for (int nf = 0; nf < NFRAG; ++nf)
            #pragma unroll
            for (int k = 0; k < 2; ++k)
                acc[A0 + f][nf] = __builtin_amdgcn_mfma_f32_16x16x32_bf16(
                    af[f][k], bfr[nf][k], acc[A0 + f][nf], 0, 0, 0);
    __builtin_amdgcn_s_setprio(0);
}

// ---- 128x192 BK=64, 80KB LDS, 2 blocks/CU, 8 waves (2M x 4N) ----------------
// Main path: R19 schedule + safe (intra-tile-only) early P1 reads. LORA tail
// blocks (orig >= MAIN): separate 128x128 loop (A=xb shared, B=wdt), EPI1.
// EPI 0: gelu(acc + bias[n]) -> bf16 apOut[m*3200 + n]   (GEMM1)
// EPI 2: acc + bias[n]       -> f32  fOut[m*768 + n]     (GEMM2)
template <int EPI, int NBX, bool LORA>
__global__ void __launch_bounds__(512, 4)
gemm4_kernel(const unsigned short* __restrict__ A, int lda,
             const unsigned short* __restrict__ Bt, int ldb,
             int kTiles, const float* __restrict__ bias,
             unsigned short* __restrict__ apOut, float* __restrict__ fOut,
             const int* __restrict__ tki, const float* __restrict__ tkp,
             const unsigned short* __restrict__ Bt2) {
    __shared__ __align__(1024) char ldsraw[81920];     // 80 KiB -> 2 blocks/CU
    char* ldsA = ldsraw;                                // [2] x 16 KB
    char* ldsB = ldsraw + 32768;                        // [2] x 24 KB (16 KB lora)

    constexpr int MAIN = NBX * (NTOK / 128);            // main-grid blocks (%8==0)
    const int orig = blockIdx.x;

    const int tid  = threadIdx.x;
    const int wave = tid >> 6;
    const int lane = tid & 63;
    const int row16 = lane & 15;
    const int quad  = lane >> 4;
    const int wm = (wave >> 2) << 6;      // 0 / 64
    const int swz = (row16 & 7) << 4;
    const int aFB = ((wm + row16) << 7) + (quad << 4);
    const int aX0 = (aFB ^ swz), aX1 = ((aFB + 64) ^ swz);

    // staging decomposition (shared): dest linear in tid; source pre-swizzled
    // with the same 3-bit involution so LDS content is swizzle-stored.
    const int d  = tid << 4;
    const int s  = d ^ (((d >> 7) & 7) << 4);
    const int sr = s >> 7;                // source row 0..63 (per 8KB unit)
    const int sc = (s & 127) >> 1;        // source col elem (16B chunk)
    const int ldsW = wave << 10;

    if constexpr (LORA) {
        if (orig >= MAIN) {
            // ---------------- LoRA tail path: 128 x 128, K = kTiles*64 ------
            const int m0 = (orig - MAIN) * 128;
            const int wn = (wave & 3) << 5;            // 0/32/64/96
            const int bFB = ((wn + row16) << 7) + (quad << 4);
            const int bX0 = (bFB ^ swz) + 32768, bX1 = ((bFB + 64) ^ swz) + 32768;
            const char* aSrc = (const char*)(A + (size_t)(m0 + sr) * lda + sc);
            const char* bSrc = (const char*)(Bt2 + (size_t)sr * CDIM + sc);
            const size_t aStep = (size_t)64 * lda * 2;
            const size_t bStep = (size_t)64 * CDIM * 2;
            auto issueA = [&](int b, int tk) {         // 128 rows = 2 GLD
                const char* sp = aSrc + (size_t)tk * 128;
                char* dp = ldsA + b * 16384 + ldsW;
                GLD(sp, dp);
                GLD(sp + aStep, dp + 8192);
            };
            auto issueB = [&](int b, int tk) {         // 128 rows = 2 GLD
                const char* sp = bSrc + (size_t)tk * 128;
                char* dp = ldsB + b * 16384 + ldsW;
                GLD(sp, dp);
                GLD(sp + bStep, dp + 8192);
            };
            auto rdA = [&](int base, int slot, bf16x8 (&af)[2][2]) {
                const int o = base + slot * 4096;
                af[0][0] = *(const bf16x8*)(ldsraw + aX0 + o);
                af[0][1] = *(const bf16x8*)(ldsraw + aX1 + o);
                af[1][0] = *(const bf16x8*)(ldsraw + aX0 + o + 2048);
                af[1][1] = *(const bf16x8*)(ldsraw + aX1 + o + 2048);
            };
            auto rdB = [&](int base, bf16x8 (&bfr)[2][2]) {
                #pragma unroll
                for (int nf = 0; nf < 2; ++nf) {
                    bfr[nf][0] = *(const bf16x8*)(ldsraw + bX0 + base + nf * 2048);
                    bfr[nf][1] = *(const bf16x8*)(ldsraw + bX1 + base + nf * 2048);
                }
            };
            f32x4 acc[4][2] = {};
            bf16x8 af0[2][2], af1[2][2], bfr0[2][2], bfr1[2][2];
            issueB(0, 0); issueA(0, 0); issueB(1, 1);
            asm volatile("s_waitcnt vmcnt(2)" ::: "memory");
            __builtin_amdgcn_s_barrier();
            __builtin_amdgcn_sched_barrier(0);
            const int nIter = kTiles >> 1;
            for (int it = 0; it < nIter; ++it) {
                const int t  = it * 2;
                const int t2 = (t + 2 < kTiles) ? t + 2 : 0;
                const int t3 = (t + 3 < kTiles) ? t + 3 : 0;

                rdA(0, 0, af0); rdB(0, bfr0);          // P0(t) frags, buf0 (post-barrier)
                phaseC<2, 0>(acc, af0, bfr0, [&]{ issueA(1, t + 1); });
                rdA(0, 1, af1);                        // intra-tile early (safe)
                __builtin_amdgcn_sched_barrier(0);
                __builtin_amdgcn_s_barrier();

                phaseC<2, 2>(acc, af1, bfr0, [&]{ issueB(0, t2); });
                asm volatile("s_waitcnt vmcnt(2)" ::: "memory");
                __builtin_amdgcn_s_barrier();
                __builtin_amdgcn_sched_barrier(0);

                rdA(16384, 0, af0); rdB(16384, bfr1);  // P0(t+1) frags, buf1
                phaseC<2, 0>(acc, af0, bfr1, [&]{ issueA(0, t2); });
                rdA(16384, 1, af1);                    // intra-tile early (safe)
                __builtin_amdgcn_sched_barrier(0);
                __builtin_amdgcn_s_barrier();

                phaseC<2, 2>(acc, af1, bfr1, [&]{ issueB(1, t3); });
                asm volatile("s_waitcnt vmcnt(2)" ::: "memory");
                __builtin_amdgcn_s_barrier();
                __builtin_amdgcn_sched_barrier(0);
            }
            asm volatile("s_waitcnt vmcnt(0)" ::: "memory");
            // R19-exact epilogue: m = m0+wm+mi*16+quad*4+i ; col = wn+nf*16+row16
            #pragma unroll
            for (int mi = 0; mi < 4; ++mi) {
                #pragma unroll
                for (int i = 0; i < 4; ++i) {
                    const int m = m0 + wm + mi * 16 + quad * 4 + i;
                    const int i0 = tki[m * 2], i1 = tki[m * 2 + 1];
                    const float p0 = tkp[m * 2], p1 = tkp[m * 2 + 1];
                    #pragma unroll
                    for (int nf = 0; nf < 2; ++nf) {
                        const int col = wn + nf * 16 + row16;
                        const int e = col >> 4;
                        float wt = (i0 == e ? p0 : 0.f) + (i1 == e ? p1 : 0.f);
                        apOut[(size_t)m * KBIG + 3072 + col] =
                            f2bf(gelu_fast(acc[mi][nf][i]) * wt);
                    }
                }
            }
            return;
        }
    }

    // ---------------- main path (R19 schedule + safe early P1 reads) ---------
    // bijective XCD swizzle (MAIN%8==0), bx-fast: each XCD's contiguous wgid
    // chunk shares A row-panels (L2 dedup).
    constexpr int qq = MAIN / 8;
    const int xcd = orig & 7, within = orig >> 3;
    const int wgid = xcd * qq + within;
    const int bx = wgid % NBX, by = wgid / NBX;

    const int m0 = by * 128;
    const int n0 = bx * 192;
    const int wn = (wave & 3) * 48;       // 0 / 48 / 96 / 144
    const int bFB = ((wn + row16) << 7) + (quad << 4);
    const int bX0 = (bFB ^ swz) + 32768, bX1 = ((bFB + 64) ^ swz) + 32768;

    const char* aSrc = (const char*)(A + (size_t)(m0 + sr) * lda + sc);
    const char* bSrc = (const char*)(Bt + (size_t)(n0 + sr) * ldb + sc);
    const size_t aStep = (size_t)64 * lda * 2;   // 64 rows, bytes
    const size_t bStep = (size_t)64 * ldb * 2;

    auto issueA = [&](int b, int tk) {           // 128 rows = 2 GLD
        const char* sp = aSrc + (size_t)tk * 128;
        char* dp = ldsA + b * 16384 + ldsW;
        GLD(sp, dp);
        GLD(sp + aStep, dp + 8192);
    };
    auto issueB = [&](int b, int tk) {           // 192 rows = 3 GLD
        const char* sp = bSrc + (size_t)tk * 128;
        char* dp = ldsB + b * 24576 + ldsW;
        GLD(sp, dp);
        GLD(sp + bStep, dp + 8192);
        GLD(sp + 2 * bStep, dp + 16384);
    };
    auto rdA = [&](int base, int slot, bf16x8 (&af)[2][2]) {
        const int o = base + slot * 4096;
        af[0][0] = *(const bf16x8*)(ldsraw + aX0 + o);
        af[0][1] = *(const bf16x8*)(ldsraw + aX1 + o);
        af[1][0] = *(const bf16x8*)(ldsraw + aX0 + o + 2048);
        af[1][1] = *(const bf16x8*)(ldsraw + aX1 + o + 2048);
    };
    auto rdB = [&](int base, bf16x8 (&bfr)[3][2]) {
        #pragma unroll
        for (int nf = 0; nf < 3; ++nf) {
            bfr[nf][0] = *(const bf16x8*)(ldsraw + bX0 + base + nf * 2048);
            bfr[nf][1] = *(const bf16x8*)(ldsraw + bX1 + base + nf * 2048);
        }
    };

    f32x4 acc[4][3] = {};
    bf16x8 af0[2][2], af1[2][2], bfr0[3][2], bfr1[3][2];

    // prologue: B(0)->b0, A(0)->a0, B(1)->b1; leave B(1)'s 3 outstanding
    issueB(0, 0);
    issueA(0, 0);
    issueB(1, 1);
    asm volatile("s_waitcnt vmcnt(3)" ::: "memory");
    __builtin_amdgcn_s_barrier();
    __builtin_amdgcn_sched_barrier(0);

    const int nIter = kTiles >> 1;
    for (int it = 0; it < nIter; ++it) {
        const int t  = it * 2;
        const int t2 = (t + 2 < kTiles) ? t + 2 : 0;   // clamped (harmless re-stage)
        const int t3 = (t + 3 < kTiles) ? t + 3 : 0;

        rdA(0, 0, af0); rdB(0, bfr0);                 // P0(t) frags, buf0 (post-barrier)
        phaseC<3, 0>(acc, af0, bfr0, [&]{ issueA(1, t + 1); });
        rdA(0, 1, af1);                               // P1(t) slices, buf0-A (safe early)
        __builtin_amdgcn_sched_barrier(0);
        __builtin_amdgcn_s_barrier();

        phaseC<3, 2>(acc, af1, bfr0, [&]{ issueB(0, t2); });
        asm volatile("s_waitcnt vmcnt(3)" ::: "memory");   // own prefetch tail
        __builtin_amdgcn_s_barrier();                      // all waves' t+1 landed
        __builtin_amdgcn_sched_barrier(0);

        rdA(16384, 0, af0); rdB(24576, bfr1);         // P0(t+1) frags, buf1
        phaseC<3, 0>(acc, af0, bfr1, [&]{ issueA(0, t2); });
        rdA(16384, 1, af1);                           // P1(t+1) slices, buf1-A (safe early)
        __builtin_amdgcn_sched_barrier(0);
        __builtin_amdgcn_s_barrier();

        phaseC<3, 2>(acc, af1, bfr1, [&]{ issueB(1, t3); });
        asm volatile("s_waitcnt vmcnt(3)" ::: "memory");   // own prefetch tail
        __builtin_amdgcn_s_barrier();                      // all waves' t+2 landed
        __builtin_amdgcn_sched_barrier(0);
    }
    asm volatile("s_waitcnt vmcnt(0)" ::: "memory");

    // R19-exact epilogue: m = m0+wm+mi*16+quad*4+i ; col = n0+wn+nf*16+row16
    float bv[3];
    #pragma unroll
    for (int nf = 0; nf < 3; ++nf) bv[nf] = bias[n0 + wn + nf * 16 + row16];
    #pragma unroll
    for (int mi = 0; mi < 4; ++mi) {
        #pragma unroll
        for (int i = 0; i < 4; ++i) {
            const int m = m0 + wm + mi * 16 + quad * 4 + i;
            #pragma unroll
            for (int nf = 0; nf < 3; ++nf) {
                const int col = n0 + wn + nf * 16 + row16;
                float v = acc[mi][nf][i] + bv[nf];
                if (EPI == 0) apOut[(size_t)m * KBIG + col] = f2bf(gelu_fast(v));
                else          fOut[(size_t)m * CDIM + col] = v;
            }
        }
    }
}

// ---------------- launch ----------------

extern "C" void kernel_launch(void* const* d_in, const int* in_sizes, int n_in,
                              void* d_out, int out_size, void* d_ws, size_t ws_size,
                              hipStream_t stream) {
    const float* x   = (const float*)d_in[0];
    const float* tkp = (const float*)d_in[1];
    const int*   tki = (const int*)d_in[2];
    const float* w1  = (const float*)d_in[3];
    const float* b1  = (const float*)d_in[4];
    const float* w2  = (const float*)d_in[5];
    const float* b2  = (const float*)d_in[6];
    const float* wdn = (const float*)d_in[7];
    const float* wup = (const float*)d_in[8];
    float* out = (float*)d_out;

    unsigned short* xb  = (unsigned short*)d_ws;
    unsigned short* w1t = xb  + (size_t)NTOK * CDIM;      // 3072 x 768
    unsigned short* B2t = w1t + (size_t)HIDDIM * CDIM;    // 768 x 3200
    unsigned short* wdt = B2t + (size_t)CDIM * KBIG;      // 128 x 768
    unsigned short* Ap  = wdt + (size_t)128 * CDIM;       // 12544 x 3200

    prep_kernel<<<dim3(10968), 256, 0, stream>>>(x, w1, w2, wup, wdn,
                                                 xb, w1t, B2t, wdt);

    // GEMM1 + GEMMd fused grid: 1568 main blocks (128x192) + 98 LoRA tail
    // blocks (128x128, dispatched last -> fill the scheduling tail).
    gemm4_kernel<0, HIDDIM / 192, true>
        <<<dim3((HIDDIM / 192 + 1) * (NTOK / 128)), 512, 0, stream>>>(
        xb, CDIM, w1t, CDIM, CDIM / 64, b1, Ap, nullptr, tki, tkp, wdt);
    // GEMM2: out = Ap @ B2t^T + b2 ; 128x192, 2 blocks/CU, 392 blocks swizzled
    gemm4_kernel<2, CDIM / 192, false>
        <<<dim3((CDIM / 192) * (NTOK / 128)), 512, 0, stream>>>(
        Ap, KBIG, B2t, KBIG, KBIG / 64, b2, nullptr, out, nullptr, nullptr, nullptr);
}